// Round 4
// baseline (82.035 us; speedup 1.0000x reference)
//
#include <hip/hip_runtime.h>

#define H  544
#define W  960
#define T  8
#define R  4
#define HB (H / T)    // 68
#define WB (W / T)    // 120
#define NB (HB * WB)  // 8160
#define NC 81         // (2R+1)^2
#define WIN 16        // T + 2R
#define SPB 3         // sub-blocks per wave
#define GRID (NB / (4 * SPB))   // 680 workgroups x 4 waves x 3 = 8160
#define TAG 0x51C0u

__device__ __forceinline__ int iclamp(int v, int lo, int hi) {
    return v < lo ? lo : (v > hi ? hi : v);
}

// ---- compile-time spiral table: rank (0-based) -> cell packed (wy<<4)|wx ----
struct SpiralTab { int v[NC]; };

__host__ __device__ constexpr SpiralTab make_spiral() {
    SpiralTab t{};
    int n = 0;
    for (int dy = 0; dy <= R; ++dy) {
        for (int dir = 0; dir < 4; ++dir) {
            int limit = (dir == 0 && dy == 0) ? 1 : dy;
            for (int dx = -dy; dx < limit; ++dx) {
                int wx, wy;
                if (dir == 0)      { wx = R + dx; wy = R + dy; }
                else if (dir == 1) { wx = R + dy; wy = R - dx; }
                else if (dir == 2) { wx = R - dx; wy = R - dy; }
                else               { wx = R - dy; wy = R + dx; }
                t.v[n] = (wy << 4) | wx;
                ++n;
            }
        }
    }
    return t;
}

static __constant__ SpiralTab SPIR = make_spiral();

__device__ __forceinline__ unsigned int sadu8(unsigned int a, unsigned int b, unsigned int acc) {
#if __has_builtin(__builtin_amdgcn_sad_u8)
    return __builtin_amdgcn_sad_u8(a, b, acc);
#else
    unsigned int d;
    asm("v_sad_u8 %0, %1, %2, %3" : "=v"(d) : "v"(a), "v"(b), "v"(acc));
    return d;
#endif
}

__device__ __forceinline__ unsigned int alignb(unsigned int hi, unsigned int lo, unsigned int sh) {
#if __has_builtin(__builtin_amdgcn_alignbyte)
    return __builtin_amdgcn_alignbyte(hi, lo, sh);
#else
    unsigned int d;
    asm("v_alignbyte_b32 %0, %1, %2, %3" : "=v"(d) : "v"(hi), "v"(lo), "v"(sh));
    return d;
#endif
}

// Exact fp32 association ((a + 2*b) + c)*0.25, no FMA contraction.
#define VERT(a, b, c) (__fmul_rn(__fadd_rn(__fadd_rn((a), __fmul_rn(2.0f, (b))), (c)), 0.25f))
#define QU(h) ((unsigned int)fminf(fmaxf(rintf(__fmul_rn((h), 255.0f)), 0.0f), 255.0f))

__device__ __forceinline__ void msort(float& a, float& b) {
    float mn = fminf(a, b), mx = fmaxf(a, b);
    a = mn; b = mx;
}

__device__ __forceinline__ float median9(float p[9]) {
    msort(p[1], p[2]); msort(p[4], p[5]); msort(p[7], p[8]);
    msort(p[0], p[1]); msort(p[3], p[4]); msort(p[6], p[7]);
    msort(p[1], p[2]); msort(p[4], p[5]); msort(p[7], p[8]);
    msort(p[0], p[3]); msort(p[5], p[8]); msort(p[4], p[7]);
    msort(p[3], p[6]); msort(p[1], p[4]); msort(p[2], p[5]);
    msort(p[4], p[7]); msort(p[4], p[2]); msort(p[6], p[4]);
    msort(p[4], p[2]);
    return p[4];
}

__device__ __forceinline__ unsigned int wait_word(unsigned int* p) {
    unsigned int v = __hip_atomic_load(p, __ATOMIC_RELAXED, __HIP_MEMORY_SCOPE_AGENT);
    while ((v >> 16) != TAG) {
        __builtin_amdgcn_s_sleep(1);
        v = __hip_atomic_load(p, __ATOMIC_RELAXED, __HIP_MEMORY_SCOPE_AGENT);
    }
    return v;
}

// Single fused kernel: blur + SAD + spiral argmin (phase 1), then
// median + Lucas-Kanade (phase 2). Cross-block dependency (median needs
// neighbor vecs) handled by tagged-word spin: data rides inside one u32.
// 680 blocks, __launch_bounds__(256,4) -> >=4 blocks/CU capacity (1024),
// so all blocks are co-resident and the spin cannot deadlock.
__global__ void __launch_bounds__(256, 4)
k_fused(const float* __restrict__ cur, const float* __restrict__ prev,
        unsigned int* __restrict__ vecw, float* __restrict__ out) {
    __shared__ float vb[4][WIN][20];         // vert blur prev, cols bx0-5..+12
    __shared__ float vc[4][10][12];          // vert blur cur, rows by0-1..+8, cols bx0-2..+9
    __shared__ uint4 regionS[4][SPB][WIN];   // quantized prev 16x16 bytes
    __shared__ uint2 tmplS[4][SPB][T];       // quantized cur 8x8 bytes
    __shared__ float gyS[4][SPB][28];        // gradient ring
    __shared__ float gxS[4][SPB][28];

    const int wv   = (int)(threadIdx.x >> 6);
    const int lane = (int)(threadIdx.x & 63);
    const int waveId = (int)blockIdx.x * 4 + wv;

    // ring pixel mapping (28 border pixels of an 8x8 tile)
    int rty, rtx;
    {
        int k = (lane < 28) ? lane : 0;
        if (k < 8)       { rty = 0;      rtx = k;      }
        else if (k < 16) { rty = T - 1;  rtx = k - 8;  }
        else if (k < 22) { rty = k - 15; rtx = 0;      }
        else             { rty = k - 21; rtx = T - 1;  }
    }

    // ---------------- phase 1: blur + SAD per sub-block ----------------
    for (int s = 0; s < SPB; ++s) {
        int bidx = waveId * SPB + s;
        int byi = bidx / WB, bxi = bidx % WB;
        int by0 = byi * T, bx0 = bxi * T;

        // vertical blur prev: 16 rows x 18 cols
        for (int e = lane; e < WIN * 18; e += 64) {
            int ry = e / 18, cx = e - ry * 18;
            int gy = iclamp(by0 - R + ry, 0, H - 1);
            int gx = iclamp(bx0 - 5 + cx, 0, W - 1);
            int ym = iclamp(gy - 1, 0, H - 1) * W;
            int yp = iclamp(gy + 1, 0, H - 1) * W;
            vb[wv][ry][cx] = VERT(prev[ym + gx], prev[gy * W + gx], prev[yp + gx]);
        }
        // vertical blur cur: 10 rows x 12 cols
        for (int e = lane; e < 120; e += 64) {
            int ry = e / 12, cx = e - ry * 12;
            int gy = iclamp(by0 - 1 + ry, 0, H - 1);
            int gx = iclamp(bx0 - 2 + cx, 0, W - 1);
            int ym = iclamp(gy - 1, 0, H - 1) * W;
            int yp = iclamp(gy + 1, 0, H - 1) * W;
            vc[wv][ry][cx] = VERT(cur[ym + gx], cur[gy * W + gx], cur[yp + gx]);
        }
        __syncthreads();

        // horizontal + quantize prev 16x16 -> region bytes
        {
            unsigned char* regB = (unsigned char*)&regionS[wv][s][0];
            int base = bx0 - 5;
            for (int e = lane; e < WIN * WIN; e += 64) {
                int ry = e >> 4, rx = e & 15;
                int gxp = iclamp(bx0 - R + rx, 0, W - 1);
                int xm = (gxp > 0) ? gxp - 1 : 0;
                int xp = (gxp < W - 1) ? gxp + 1 : W - 1;
                float h = VERT(vb[wv][ry][xm - base], vb[wv][ry][gxp - base], vb[wv][ry][xp - base]);
                regB[ry * 16 + rx] = (unsigned char)QU(h);
            }
        }
        // horizontal + quantize cur 8x8 template
        {
            int ty = lane >> 3, tx = lane & 7;
            // h at col bx0+tx uses vert cols bx0+tx-1..+1 -> vc cx = tx+1..tx+3
            float hT = VERT(vc[wv][ty + 1][tx + 1], vc[wv][ty + 1][tx + 2], vc[wv][ty + 1][tx + 3]);
            ((unsigned char*)&tmplS[wv][s][0])[ty * 8 + tx] = (unsigned char)QU(hT);
        }
        // gradient ring from vc: h(r,c) = VERT(vc[r+1][c+1..c+3]), r,c in [-1,8]
        if (lane < 28) {
            int y = by0 + rty, x = bx0 + rtx;
            int rp = iclamp(y + 1, 0, H - 1) - by0;
            int rm = iclamp(y - 1, 0, H - 1) - by0;
            int cp = iclamp(x + 1, 0, W - 1) - bx0;
            int cm = iclamp(x - 1, 0, W - 1) - bx0;
            float hyp = VERT(vc[wv][rp + 1][rtx + 1], vc[wv][rp + 1][rtx + 2], vc[wv][rp + 1][rtx + 3]);
            float hym = VERT(vc[wv][rm + 1][rtx + 1], vc[wv][rm + 1][rtx + 2], vc[wv][rm + 1][rtx + 3]);
            float hxp = VERT(vc[wv][rty + 1][cp + 1], vc[wv][rty + 1][cp + 2], vc[wv][rty + 1][cp + 3]);
            float hxm = VERT(vc[wv][rty + 1][cm + 1], vc[wv][rty + 1][cm + 2], vc[wv][rty + 1][cm + 3]);
            gyS[wv][s][lane] = (hyp - hym) * 0.5f;
            gxS[wv][s][lane] = (hxp - hxm) * 0.5f;
        }
        __syncthreads();

        // SAD, lane = spiral rank (ranks {lane, lane+64})
        unsigned int t0[T], t1[T];
#pragma unroll
        for (int ty = 0; ty < T; ++ty) {
            uint2 tt = tmplS[wv][s][ty];
            t0[ty] = tt.x;
            t1[ty] = tt.y;
        }
        int cell0 = SPIR.v[lane];
        int dy0 = cell0 >> 4, dx0 = cell0 & 15;
        bool v1 = (lane + 64) < NC;
        int cell1 = SPIR.v[v1 ? (lane + 64) : 0];
        int dy1 = cell1 >> 4, dx1 = cell1 & 15;

        unsigned int sad0 = 0, sad1 = 0;
        int q0 = dx0 >> 2; unsigned int r0 = (unsigned int)(dx0 & 3);
        int q1 = dx1 >> 2; unsigned int r1 = (unsigned int)(dx1 & 3);
#pragma unroll
        for (int ty = 0; ty < T; ++ty) {
            {
                uint4 row = regionS[wv][s][ty + dy0];
                unsigned int w0 = (q0 == 0) ? row.x : ((q0 == 1) ? row.y : row.z);
                unsigned int w1 = (q0 == 0) ? row.y : ((q0 == 1) ? row.z : row.w);
                unsigned int w2 = (q0 == 0) ? row.z : row.w;
                sad0 = sadu8(alignb(w1, w0, r0), t0[ty], sad0);
                sad0 = sadu8(alignb(w2, w1, r0), t1[ty], sad0);
            }
            if (v1) {
                uint4 row = regionS[wv][s][ty + dy1];
                unsigned int w0 = (q1 == 0) ? row.x : ((q1 == 1) ? row.y : row.z);
                unsigned int w1 = (q1 == 0) ? row.y : ((q1 == 1) ? row.z : row.w);
                unsigned int w2 = (q1 == 0) ? row.z : row.w;
                sad1 = sadu8(alignb(w1, w0, r1), t0[ty], sad1);
                sad1 = sadu8(alignb(w2, w1, r1), t1[ty], sad1);
            }
        }
        int key = (int)((sad0 << 7) | (unsigned int)lane);
        if (v1) {
            int k1 = (int)((sad1 << 7) | (unsigned int)(lane + 64));
            key = min(key, k1);
        }
#pragma unroll
        for (int off = 32; off > 0; off >>= 1)
            key = min(key, __shfl_xor(key, off));
        if (lane == 0) {
            int rank = key & 127;
            int cell = SPIR.v[rank];
            int vy = -((cell >> 4) - R);    // in [-4,4]
            int vx = -((cell & 15) - R);
            unsigned int word = (TAG << 16) | ((unsigned int)(vy + 8) << 8) | (unsigned int)(vx + 8);
            __hip_atomic_store(&vecw[bidx], word, __ATOMIC_RELAXED, __HIP_MEMORY_SCOPE_AGENT);
        }
    }
    __syncthreads();

    // ---------------- phase 2: median + Lucas-Kanade ----------------
    for (int s = 0; s < SPB; ++s) {
        int bidx = waveId * SPB + s;
        int byi = bidx / WB, bxi = bidx % WB;
        int by0 = byi * T, bx0 = bxi * T;

        float py[9], px[9];
#pragma unroll
        for (int i = 0; i < 3; ++i)
#pragma unroll
            for (int j = 0; j < 3; ++j) {
                int nb = iclamp(byi + i - 1, 0, HB - 1) * WB + iclamp(bxi + j - 1, 0, WB - 1);
                unsigned int wd = wait_word(&vecw[nb]);
                py[i * 3 + j] = (float)((int)((wd >> 8) & 255u) - 8);
                px[i * 3 + j] = (float)((int)(wd & 255u) - 8);
            }
        float vmy = median9(py);
        float vmx = median9(px);

        int med_y = iclamp((int)rintf(vmy), -R, R);
        int med_x = iclamp((int)rintf(vmx), -R, R);
        int off_y = -med_y, off_x = -med_x;   // vec stores negated offsets

        bool act = lane < 28;
        float a = 0.f, b = 0.f, d = 0.f, p = 0.f, q = 0.f;
        if (act) {
            // template byte
            unsigned int tb = ((const unsigned char*)&tmplS[wv][s][0])[rty * 8 + rtx];
            float tmplv = (float)tb / 255.0f;
            // matched byte from region: row rty+off_y+4, byte rtx+off_x+4 (always in [0,15])
            int ridx = rty + off_y + R + R;   // careful: region row = (ty+off_y)+4
            ridx = rty + off_y + 4;
            int cidx = rtx + off_x + 4;
            uint4 row = regionS[wv][s][ridx];
            unsigned int wsel = (cidx >> 2) == 0 ? row.x : ((cidx >> 2) == 1 ? row.y : ((cidx >> 2) == 2 ? row.z : row.w));
            unsigned int mb = (wsel >> ((cidx & 3) * 8)) & 255u;
            float matv = (float)mb / 255.0f;
            float gyv = gyS[wv][s][lane];
            float gxv = gxS[wv][s][lane];
            float diff = matv - tmplv;
            a = gxv * gxv;
            b = gxv * gyv;
            d = gyv * gyv;
            p = diff * gxv;
            q = diff * gyv;
        }
#pragma unroll
        for (int off = 16; off > 0; off >>= 1) {
            a += __shfl_xor(a, off);
            b += __shfl_xor(b, off);
            d += __shfl_xor(d, off);
            p += __shfl_xor(p, off);
            q += __shfl_xor(q, off);
        }
        if (lane == 0) {
            float det  = a * d - b * b;
            float safe = (det <= 1e-6f) ? 1.0f : det;
            float su = (d * p - b * q) / safe;
            float sv = (a * q - b * p) / safe;
            bool inval = (det <= 1e-6f);
            float sy = (inval || fabsf(sv) >= 1.0f) ? 0.0f : sv;
            float sx = (inval || fabsf(su) >= 1.0f) ? 0.0f : su;
            out[bidx]      = vmy + sy;
            out[NB + bidx] = vmx + sx;
        }
    }
}

extern "C" void kernel_launch(void* const* d_in, const int* in_sizes, int n_in,
                              void* d_out, int out_size, void* d_ws, size_t ws_size,
                              hipStream_t stream) {
    const float* cur  = (const float*)d_in[0];
    const float* prev = (const float*)d_in[1];
    float* out = (float*)d_out;
    unsigned int* vecw = (unsigned int*)d_ws;   // NB tagged words (ws poisoned 0xAA each call)

    k_fused<<<GRID, 256, 0, stream>>>(cur, prev, vecw, out);
}